// Round 5
// baseline (299.277 us; speedup 1.0000x reference)
//
#include <hip/hip_runtime.h>
#include <math.h>

// Problem constants (SHAPE = (1, 128, 48, 48, 48), FILTERS = (1,3,3,3,1))
#define NCH      128
#define SPATIAL  110592            // 48*48*48
#define NV4      3538944           // NCH*SPATIAL/4 total float4 groups
#define CV4      27648             // SPATIAL/4 float4 groups per channel
#define FB       512               // float4 groups per block (256 thr x 2)
#define MAIN_GRID 6912             // NV4 / FB (exact)
#define BPC      54                // CV4 / FB -> blocks per channel (exact: channel is block-uniform)
#define TAILB    129               // 1 loss block + 128 per-channel fallback blocks (mapped first)
#define THREADS  256

#define QT 21.416413017506358f     // log(2/1e-9 - 1)

typedef float v4f __attribute__((ext_vector_type(4)));

__device__ __forceinline__ float frcp(float x){ return __builtin_amdgcn_rcpf(x); }
__device__ __forceinline__ float ftanh(float x){ return 1.0f - 2.0f*frcp(__expf(2.0f*x) + 1.0f); }
__device__ __forceinline__ float fsig(float x){ return frcp(1.0f + __expf(-x)); }
__device__ __forceinline__ float fsoftplus(float x){ return fmaxf(x, 0.0f) + log1pf(__expf(-fabsf(x))); }

struct Params {
    float w0[3], w1[9], w2[9], w3[3];
    float t0[3], t1[3], t2[3];
    float B0[3], B1[3], B2[3], B3;
};

__device__ __forceinline__ Params load_params(int c,
    const float* __restrict__ m0, const float* __restrict__ b0, const float* __restrict__ f0,
    const float* __restrict__ m1, const float* __restrict__ b1, const float* __restrict__ f1,
    const float* __restrict__ m2, const float* __restrict__ b2, const float* __restrict__ f2,
    const float* __restrict__ m3, const float* __restrict__ b3)
{
    Params P;
    #pragma unroll
    for (int k=0;k<3;k++) P.w0[k]=fsoftplus(m0[c*3+k]);
    #pragma unroll
    for (int k=0;k<9;k++) P.w1[k]=fsoftplus(m1[c*9+k]);
    #pragma unroll
    for (int k=0;k<9;k++) P.w2[k]=fsoftplus(m2[c*9+k]);
    #pragma unroll
    for (int k=0;k<3;k++) P.w3[k]=fsoftplus(m3[c*3+k]);
    #pragma unroll
    for (int k=0;k<3;k++) P.t0[k]=ftanh(f0[c*3+k]);
    #pragma unroll
    for (int k=0;k<3;k++) P.t1[k]=ftanh(f1[c*3+k]);
    #pragma unroll
    for (int k=0;k<3;k++) P.t2[k]=ftanh(f2[c*3+k]);
    #pragma unroll
    for (int k=0;k<3;k++) P.B0[k]=b0[c*3+k];
    #pragma unroll
    for (int k=0;k<3;k++) P.B1[k]=b1[c*3+k];
    #pragma unroll
    for (int k=0;k<3;k++) P.B2[k]=b2[c*3+k];
    P.B3 = b3[c];
    return P;
}

template<bool USE_F>
__device__ __forceinline__ float eval_mlp(float z, const Params& P){
    float h0 = fmaf(P.w0[0], z, P.B0[0]);
    float h1 = fmaf(P.w0[1], z, P.B0[1]);
    float h2 = fmaf(P.w0[2], z, P.B0[2]);
    if (USE_F){
        h0 = fmaf(P.t0[0], ftanh(h0), h0);
        h1 = fmaf(P.t0[1], ftanh(h1), h1);
        h2 = fmaf(P.t0[2], ftanh(h2), h2);
    }
    float g0 = fmaf(P.w1[0],h0, fmaf(P.w1[1],h1, fmaf(P.w1[2],h2, P.B1[0])));
    float g1 = fmaf(P.w1[3],h0, fmaf(P.w1[4],h1, fmaf(P.w1[5],h2, P.B1[1])));
    float g2 = fmaf(P.w1[6],h0, fmaf(P.w1[7],h1, fmaf(P.w1[8],h2, P.B1[2])));
    if (USE_F){
        g0 = fmaf(P.t1[0], ftanh(g0), g0);
        g1 = fmaf(P.t1[1], ftanh(g1), g1);
        g2 = fmaf(P.t1[2], ftanh(g2), g2);
    }
    h0 = fmaf(P.w2[0],g0, fmaf(P.w2[1],g1, fmaf(P.w2[2],g2, P.B2[0])));
    h1 = fmaf(P.w2[3],g0, fmaf(P.w2[4],g1, fmaf(P.w2[5],g2, P.B2[1])));
    h2 = fmaf(P.w2[6],g0, fmaf(P.w2[7],g1, fmaf(P.w2[8],g2, P.B2[2])));
    if (USE_F){
        h0 = fmaf(P.t2[0], ftanh(h0), h0);
        h1 = fmaf(P.t2[1], ftanh(h1), h1);
        h2 = fmaf(P.t2[2], ftanh(h2), h2);
    }
    return fmaf(P.w3[0],h0, fmaf(P.w3[1],h1, fmaf(P.w3[2],h2, P.B3)));
}

__device__ __forceinline__ float lik_from_logits(float lo, float hi){
    float su = lo + hi;
    float s  = (su > 0.0f) ? -1.0f : ((su < 0.0f) ? 1.0f : 0.0f);   // -sign(lo+hi)
    float a  = fsig(s*hi);
    float b  = fsig(s*lo);
    return fmaxf(fabsf(a - b), 1e-9f);        // LIKELIHOOD_BOUND
}

// ---------------------------------------------------------------------------
// Single fused kernel, grid = TAILB + MAIN_GRID.
//   block 0        : quantiles_loss (tid<128: one channel each, 3 evals)
//   blocks 1..128  : nonlinear fallback for channel b-1 iff it has nonzero
//                    factors (early-exit in the bench case).
//   blocks 129..   : streaming fast path, channel block-uniform; issues its
//                    4 NT loads first, does the per-channel affine collapse
//                    (wave-uniform) under the load latency, early-exits
//                    (pre-store) on nonlinear channels.
// Tail blocks are at the FRONT of the grid so the loss block overlaps the
// streaming wavefront instead of running after it. Output regions are
// disjoint by construction (fast path skips exactly what fallback writes).
// Occupancy note: Little's law needs ~9 KB in-flight/CU at 6.3 TB/s; each
// wave holds 4 KB -> even 4 waves/SIMD over-covers, so the fat cold branch's
// VGPR cost cannot cost bandwidth unless it spills into the hot path.
// ---------------------------------------------------------------------------
__global__ __launch_bounds__(THREADS) void eb_fused(
    const float* __restrict__ x, const float* __restrict__ noise,
    const float* __restrict__ m0, const float* __restrict__ b0, const float* __restrict__ f0,
    const float* __restrict__ m1, const float* __restrict__ b1, const float* __restrict__ f1,
    const float* __restrict__ m2, const float* __restrict__ b2, const float* __restrict__ f2,
    const float* __restrict__ m3, const float* __restrict__ b3,
    const float* __restrict__ q, float* __restrict__ loss,
    float* __restrict__ out, float* __restrict__ lik)
{
    const int blk = blockIdx.x;
    const int tid = threadIdx.x;

    const v4f* __restrict__ x4 = (const v4f*)x;
    const v4f* __restrict__ n4 = (const v4f*)noise;
    v4f* __restrict__ o4 = (v4f*)out;
    v4f* __restrict__ l4 = (v4f*)lik;

    if (blk >= TAILB){
        // ------------------------- streaming fast path -------------------------
        const int b = blk - TAILB;
        const int c = b / BPC;               // block-uniform channel

        const int i0 = b * FB + tid;
        const int i1 = i0 + THREADS;

        // issue the memory stream immediately; everything below hides under it
        v4f xa = __builtin_nontemporal_load(x4 + i0);
        v4f xb = __builtin_nontemporal_load(x4 + i1);
        v4f na = __builtin_nontemporal_load(n4 + i0);
        v4f nb = __builtin_nontemporal_load(n4 + i1);

        // linearity check: all 9 factors of this channel zero? (uniform loads)
        float fs = 0.0f;
        #pragma unroll
        for (int k=0;k<3;k++) fs += fabsf(f0[c*3+k]) + fabsf(f1[c*3+k]) + fabsf(f2[c*3+k]);
        if (fs != 0.0f) return;              // fallback blocks own this channel

        // progressive affine collapse: logit(z) = A*z + B for this channel
        float a0 = fsoftplus(m0[c*3+0]), a1 = fsoftplus(m0[c*3+1]), a2 = fsoftplus(m0[c*3+2]);
        float o0 = b0[c*3+0],            o1 = b0[c*3+1],            o2 = b0[c*3+2];

        {   // layer 1
            float w00=fsoftplus(m1[c*9+0]), w01=fsoftplus(m1[c*9+1]), w02=fsoftplus(m1[c*9+2]);
            float w10=fsoftplus(m1[c*9+3]), w11=fsoftplus(m1[c*9+4]), w12=fsoftplus(m1[c*9+5]);
            float w20=fsoftplus(m1[c*9+6]), w21=fsoftplus(m1[c*9+7]), w22=fsoftplus(m1[c*9+8]);
            float na0 = w00*a0 + w01*a1 + w02*a2;
            float na1 = w10*a0 + w11*a1 + w12*a2;
            float na2 = w20*a0 + w21*a1 + w22*a2;
            float no0 = w00*o0 + w01*o1 + w02*o2 + b1[c*3+0];
            float no1 = w10*o0 + w11*o1 + w12*o2 + b1[c*3+1];
            float no2 = w20*o0 + w21*o1 + w22*o2 + b1[c*3+2];
            a0=na0; a1=na1; a2=na2; o0=no0; o1=no1; o2=no2;
        }
        {   // layer 2
            float w00=fsoftplus(m2[c*9+0]), w01=fsoftplus(m2[c*9+1]), w02=fsoftplus(m2[c*9+2]);
            float w10=fsoftplus(m2[c*9+3]), w11=fsoftplus(m2[c*9+4]), w12=fsoftplus(m2[c*9+5]);
            float w20=fsoftplus(m2[c*9+6]), w21=fsoftplus(m2[c*9+7]), w22=fsoftplus(m2[c*9+8]);
            float na0 = w00*a0 + w01*a1 + w02*a2;
            float na1 = w10*a0 + w11*a1 + w12*a2;
            float na2 = w20*a0 + w21*a1 + w22*a2;
            float no0 = w00*o0 + w01*o1 + w02*o2 + b2[c*3+0];
            float no1 = w10*o0 + w11*o1 + w12*o2 + b2[c*3+1];
            float no2 = w20*o0 + w21*o1 + w22*o2 + b2[c*3+2];
            a0=na0; a1=na1; a2=na2; o0=no0; o1=no1; o2=no2;
        }
        float w30=fsoftplus(m3[c*3+0]), w31=fsoftplus(m3[c*3+1]), w32=fsoftplus(m3[c*3+2]);
        const float A  = w30*a0 + w31*a1 + w32*a2;
        const float Bq = w30*o0 + w31*o1 + w32*o2 + b3[c];
        const float Bl = Bq - 0.5f*A;        // logit(o-0.5) = A*o + Bl

        v4f ov0, lv0, ov1, lv1;
        #pragma unroll
        for (int e = 0; e < 4; ++e){
            float o  = xa[e] + na[e] - 0.5f;
            float lo = fmaf(A, o, Bl);
            float hi = lo + A;
            ov0[e] = o;
            lv0[e] = lik_from_logits(lo, hi);
        }
        #pragma unroll
        for (int e = 0; e < 4; ++e){
            float o  = xb[e] + nb[e] - 0.5f;
            float lo = fmaf(A, o, Bl);
            float hi = lo + A;
            ov1[e] = o;
            lv1[e] = lik_from_logits(lo, hi);
        }

        __builtin_nontemporal_store(ov0, o4 + i0);
        __builtin_nontemporal_store(lv0, l4 + i0);
        __builtin_nontemporal_store(ov1, o4 + i1);
        __builtin_nontemporal_store(lv1, l4 + i1);
        return;
    }

    if (blk == 0){
        // ------------------------- quantiles_loss block ------------------------
        float sum = 0.0f;
        if (tid < NCH){
            Params P = load_params(tid, m0,b0,f0, m1,b1,f1, m2,b2,f2, m3,b3);
            #pragma unroll
            for (int j = 0; j < 3; ++j){
                float target = (j==0) ? -QT : ((j==1) ? 0.0f : QT);
                sum += fabsf(eval_mlp<true>(q[tid*3+j], P) - target);
            }
        }
        #pragma unroll
        for (int off = 32; off > 0; off >>= 1)
            sum += __shfl_down(sum, off, 64);
        __shared__ float red[4];
        if ((tid & 63) == 0) red[tid >> 6] = sum;
        __syncthreads();
        if (tid == 0) *loss = red[0]+red[1]+red[2]+red[3];
        return;
    }

    // --------------------- nonlinear fallback (rare path) ----------------------
    const int c = blk - 1;                   // one block per channel
    float fs = 0.0f;
    #pragma unroll
    for (int k=0;k<3;k++) fs += fabsf(f0[c*3+k]) + fabsf(f1[c*3+k]) + fabsf(f2[c*3+k]);
    if (fs == 0.0f) return;                  // fast path handled this channel

    Params P = load_params(c, m0,b0,f0, m1,b1,f1, m2,b2,f2, m3,b3);

    const int end = (c+1)*CV4;
    for (int i = c*CV4 + tid; i < end; i += THREADS){
        v4f xv = x4[i], nv = n4[i];
        v4f ov, lv;
        #pragma unroll
        for (int e = 0; e < 4; ++e){
            float o  = xv[e] + nv[e] - 0.5f;
            float lo = eval_mlp<true>(o - 0.5f, P);
            float hi = eval_mlp<true>(o + 0.5f, P);
            ov[e] = o;
            lv[e] = lik_from_logits(lo, hi);
        }
        __builtin_nontemporal_store(ov, o4 + i);
        __builtin_nontemporal_store(lv, l4 + i);
    }
}

extern "C" void kernel_launch(void* const* d_in, const int* in_sizes, int n_in,
                              void* d_out, int out_size, void* d_ws, size_t ws_size,
                              hipStream_t stream) {
    // setup_inputs() dict order:
    // 0:x 1:noise 2:m0 3:b0 4:f0 5:m1 6:b1 7:f1 8:m2 9:b2 10:f2 11:m3 12:b3 13:quantiles
    const float* x  = (const float*)d_in[0];
    const float* nz = (const float*)d_in[1];
    const float* m0 = (const float*)d_in[2];
    const float* b0 = (const float*)d_in[3];
    const float* f0 = (const float*)d_in[4];
    const float* m1 = (const float*)d_in[5];
    const float* b1 = (const float*)d_in[6];
    const float* f1 = (const float*)d_in[7];
    const float* m2 = (const float*)d_in[8];
    const float* b2 = (const float*)d_in[9];
    const float* f2 = (const float*)d_in[10];
    const float* m3 = (const float*)d_in[11];
    const float* b3 = (const float*)d_in[12];
    const float* qq = (const float*)d_in[13];

    float* out  = (float*)d_out;
    float* lik  = out + (size_t)NCH*SPATIAL;
    float* loss = lik + (size_t)NCH*SPATIAL;

    eb_fused<<<TAILB + MAIN_GRID, THREADS, 0, stream>>>(
        x, nz, m0,b0,f0, m1,b1,f1, m2,b2,f2, m3,b3, qq, loss, out, lik);
}

// Round 9
// 215.278 us; speedup vs baseline: 1.3902x; 1.3902x over previous
//
#include <hip/hip_runtime.h>
#include <math.h>

// Problem constants (SHAPE = (1, 128, 48, 48, 48), FILTERS = (1,3,3,3,1))
#define NCH      128
#define SPATIAL  110592            // 48*48*48
#define NV4      3538944           // NCH*SPATIAL/4 total float4 groups
#define CV4      27648             // SPATIAL/4 float4 groups per channel
#define FB       1024              // float4 groups per block (256 thr x 4)
#define MAIN_GRID 3456             // NV4 / FB (exact)
#define BPC      27                // CV4 / FB -> blocks per channel (exact: channel is block-uniform)
#define TAILB    129               // 1 loss block + 128 per-channel fallback blocks (mapped first)
#define THREADS  256

#define QT 21.416413017506358f     // log(2/1e-9 - 1)

typedef float v4f __attribute__((ext_vector_type(4)));

__device__ __forceinline__ float frcp(float x){ return __builtin_amdgcn_rcpf(x); }
__device__ __forceinline__ float ftanh(float x){ return 1.0f - 2.0f*frcp(__expf(2.0f*x) + 1.0f); }
__device__ __forceinline__ float fsig(float x){ return frcp(1.0f + __expf(-x)); }
// Cheap softplus: native v_log instead of libm log1pf. y = e^-|x| in (0,1],
// so log(1+y) naive loses ~1 ulp absolute — negligible vs test tolerance.
// (Round-5 counters: VALUBusy 92% dominated by log1pf-based collapse.)
__device__ __forceinline__ float fsoftplus(float x){ return fmaxf(x, 0.0f) + __logf(1.0f + __expf(-fabsf(x))); }

struct Params {
    float w0[3], w1[9], w2[9], w3[3];
    float t0[3], t1[3], t2[3];
    float B0[3], B1[3], B2[3], B3;
};

__device__ __forceinline__ Params load_params(int c,
    const float* __restrict__ m0, const float* __restrict__ b0, const float* __restrict__ f0,
    const float* __restrict__ m1, const float* __restrict__ b1, const float* __restrict__ f1,
    const float* __restrict__ m2, const float* __restrict__ b2, const float* __restrict__ f2,
    const float* __restrict__ m3, const float* __restrict__ b3)
{
    Params P;
    #pragma unroll
    for (int k=0;k<3;k++) P.w0[k]=fsoftplus(m0[c*3+k]);
    #pragma unroll
    for (int k=0;k<9;k++) P.w1[k]=fsoftplus(m1[c*9+k]);
    #pragma unroll
    for (int k=0;k<9;k++) P.w2[k]=fsoftplus(m2[c*9+k]);
    #pragma unroll
    for (int k=0;k<3;k++) P.w3[k]=fsoftplus(m3[c*3+k]);
    #pragma unroll
    for (int k=0;k<3;k++) P.t0[k]=ftanh(f0[c*3+k]);
    #pragma unroll
    for (int k=0;k<3;k++) P.t1[k]=ftanh(f1[c*3+k]);
    #pragma unroll
    for (int k=0;k<3;k++) P.t2[k]=ftanh(f2[c*3+k]);
    #pragma unroll
    for (int k=0;k<3;k++) P.B0[k]=b0[c*3+k];
    #pragma unroll
    for (int k=0;k<3;k++) P.B1[k]=b1[c*3+k];
    #pragma unroll
    for (int k=0;k<3;k++) P.B2[k]=b2[c*3+k];
    P.B3 = b3[c];
    return P;
}

template<bool USE_F>
__device__ __forceinline__ float eval_mlp(float z, const Params& P){
    float h0 = fmaf(P.w0[0], z, P.B0[0]);
    float h1 = fmaf(P.w0[1], z, P.B0[1]);
    float h2 = fmaf(P.w0[2], z, P.B0[2]);
    if (USE_F){
        h0 = fmaf(P.t0[0], ftanh(h0), h0);
        h1 = fmaf(P.t0[1], ftanh(h1), h1);
        h2 = fmaf(P.t0[2], ftanh(h2), h2);
    }
    float g0 = fmaf(P.w1[0],h0, fmaf(P.w1[1],h1, fmaf(P.w1[2],h2, P.B1[0])));
    float g1 = fmaf(P.w1[3],h0, fmaf(P.w1[4],h1, fmaf(P.w1[5],h2, P.B1[1])));
    float g2 = fmaf(P.w1[6],h0, fmaf(P.w1[7],h1, fmaf(P.w1[8],h2, P.B1[2])));
    if (USE_F){
        g0 = fmaf(P.t1[0], ftanh(g0), g0);
        g1 = fmaf(P.t1[1], ftanh(g1), g1);
        g2 = fmaf(P.t1[2], ftanh(g2), g2);
    }
    h0 = fmaf(P.w2[0],g0, fmaf(P.w2[1],g1, fmaf(P.w2[2],g2, P.B2[0])));
    h1 = fmaf(P.w2[3],g0, fmaf(P.w2[4],g1, fmaf(P.w2[5],g2, P.B2[1])));
    h2 = fmaf(P.w2[6],g0, fmaf(P.w2[7],g1, fmaf(P.w2[8],g2, P.B2[2])));
    if (USE_F){
        h0 = fmaf(P.t2[0], ftanh(h0), h0);
        h1 = fmaf(P.t2[1], ftanh(h1), h1);
        h2 = fmaf(P.t2[2], ftanh(h2), h2);
    }
    return fmaf(P.w3[0],h0, fmaf(P.w3[1],h1, fmaf(P.w3[2],h2, P.B3)));
}

__device__ __forceinline__ float lik_from_logits(float lo, float hi){
    float su = lo + hi;
    float s  = (su > 0.0f) ? -1.0f : ((su < 0.0f) ? 1.0f : 0.0f);   // -sign(lo+hi)
    float a  = fsig(s*hi);
    float b  = fsig(s*lo);
    return fmaxf(fabsf(a - b), 1e-9f);        // LIKELIHOOD_BOUND
}

// ---------------------------------------------------------------------------
// Single fused kernel, grid = TAILB + MAIN_GRID.
//   block 0        : quantiles_loss
//   blocks 1..128  : nonlinear fallback for channel b-1 iff nonzero factors
//   blocks 129..   : streaming fast path, 4 float4/thread, channel
//                    block-uniform; 8 NT loads issued first, then the cheap
//                    per-channel affine collapse, then compute + NT stores.
// Round-5 counters (135.6us, VALUBusy 92%, HBM 15.7%): VALU-bound on the
// collapse (log1pf softplus x24, re-executed per wave). This version: native
// __logf softplus (~20x fewer collapse cycles) + FB 512->1024 (2x fewer
// collapse executions). Streaming core numerics unchanged (verified round 5,
// absmax 0.03125 pass).
// ---------------------------------------------------------------------------
__global__ __launch_bounds__(THREADS) void eb_fused(
    const float* __restrict__ x, const float* __restrict__ noise,
    const float* __restrict__ m0, const float* __restrict__ b0, const float* __restrict__ f0,
    const float* __restrict__ m1, const float* __restrict__ b1, const float* __restrict__ f1,
    const float* __restrict__ m2, const float* __restrict__ b2, const float* __restrict__ f2,
    const float* __restrict__ m3, const float* __restrict__ b3,
    const float* __restrict__ q, float* __restrict__ loss,
    float* __restrict__ out, float* __restrict__ lik)
{
    const int blk = blockIdx.x;
    const int tid = threadIdx.x;

    const v4f* __restrict__ x4 = (const v4f*)x;
    const v4f* __restrict__ n4 = (const v4f*)noise;
    v4f* __restrict__ o4 = (v4f*)out;
    v4f* __restrict__ l4 = (v4f*)lik;

    if (blk >= TAILB){
        // ------------------------- streaming fast path -------------------------
        const int b = blk - TAILB;
        const int c = b / BPC;               // block-uniform channel

        const int i0 = b * FB + tid;         // 4 chunks: i0 + k*THREADS

        // issue the full memory stream immediately; collapse hides under it
        v4f xa0 = __builtin_nontemporal_load(x4 + i0);
        v4f xa1 = __builtin_nontemporal_load(x4 + i0 + 1*THREADS);
        v4f xa2 = __builtin_nontemporal_load(x4 + i0 + 2*THREADS);
        v4f xa3 = __builtin_nontemporal_load(x4 + i0 + 3*THREADS);
        v4f na0 = __builtin_nontemporal_load(n4 + i0);
        v4f na1 = __builtin_nontemporal_load(n4 + i0 + 1*THREADS);
        v4f na2 = __builtin_nontemporal_load(n4 + i0 + 2*THREADS);
        v4f na3 = __builtin_nontemporal_load(n4 + i0 + 3*THREADS);

        // linearity check: all 9 factors of this channel zero? (uniform loads)
        float fs = 0.0f;
        #pragma unroll
        for (int k=0;k<3;k++) fs += fabsf(f0[c*3+k]) + fabsf(f1[c*3+k]) + fabsf(f2[c*3+k]);
        if (fs != 0.0f) return;              // fallback blocks own this channel

        // progressive affine collapse: logit(z) = A*z + B for this channel
        float a0 = fsoftplus(m0[c*3+0]), a1 = fsoftplus(m0[c*3+1]), a2 = fsoftplus(m0[c*3+2]);
        float o0 = b0[c*3+0],            o1 = b0[c*3+1],            o2 = b0[c*3+2];

        {   // layer 1
            float w00=fsoftplus(m1[c*9+0]), w01=fsoftplus(m1[c*9+1]), w02=fsoftplus(m1[c*9+2]);
            float w10=fsoftplus(m1[c*9+3]), w11=fsoftplus(m1[c*9+4]), w12=fsoftplus(m1[c*9+5]);
            float w20=fsoftplus(m1[c*9+6]), w21=fsoftplus(m1[c*9+7]), w22=fsoftplus(m1[c*9+8]);
            float na_0 = w00*a0 + w01*a1 + w02*a2;
            float na_1 = w10*a0 + w11*a1 + w12*a2;
            float na_2 = w20*a0 + w21*a1 + w22*a2;
            float no_0 = w00*o0 + w01*o1 + w02*o2 + b1[c*3+0];
            float no_1 = w10*o0 + w11*o1 + w12*o2 + b1[c*3+1];
            float no_2 = w20*o0 + w21*o1 + w22*o2 + b1[c*3+2];
            a0=na_0; a1=na_1; a2=na_2; o0=no_0; o1=no_1; o2=no_2;
        }
        {   // layer 2
            float w00=fsoftplus(m2[c*9+0]), w01=fsoftplus(m2[c*9+1]), w02=fsoftplus(m2[c*9+2]);
            float w10=fsoftplus(m2[c*9+3]), w11=fsoftplus(m2[c*9+4]), w12=fsoftplus(m2[c*9+5]);
            float w20=fsoftplus(m2[c*9+6]), w21=fsoftplus(m2[c*9+7]), w22=fsoftplus(m2[c*9+8]);
            float na_0 = w00*a0 + w01*a1 + w02*a2;
            float na_1 = w10*a0 + w11*a1 + w12*a2;
            float na_2 = w20*a0 + w21*a1 + w22*a2;
            float no_0 = w00*o0 + w01*o1 + w02*o2 + b2[c*3+0];
            float no_1 = w10*o0 + w11*o1 + w12*o2 + b2[c*3+1];
            float no_2 = w20*o0 + w21*o1 + w22*o2 + b2[c*3+2];
            a0=na_0; a1=na_1; a2=na_2; o0=no_0; o1=no_1; o2=no_2;
        }
        float w30=fsoftplus(m3[c*3+0]), w31=fsoftplus(m3[c*3+1]), w32=fsoftplus(m3[c*3+2]);
        const float A  = w30*a0 + w31*a1 + w32*a2;
        const float Bq = w30*o0 + w31*o1 + w32*o2 + b3[c];
        const float Bl = Bq - 0.5f*A;        // logit(o-0.5) = A*o + Bl

        #pragma unroll
        for (int k = 0; k < 4; ++k){
            v4f xv = (k==0)?xa0:((k==1)?xa1:((k==2)?xa2:xa3));
            v4f nv = (k==0)?na0:((k==1)?na1:((k==2)?na2:na3));
            v4f ov, lv;
            #pragma unroll
            for (int e = 0; e < 4; ++e){
                float o  = xv[e] + nv[e] - 0.5f;
                float lo = fmaf(A, o, Bl);
                float hi = lo + A;
                ov[e] = o;
                lv[e] = lik_from_logits(lo, hi);
            }
            __builtin_nontemporal_store(ov, o4 + i0 + k*THREADS);
            __builtin_nontemporal_store(lv, l4 + i0 + k*THREADS);
        }
        return;
    }

    if (blk == 0){
        // ------------------------- quantiles_loss block ------------------------
        float sum = 0.0f;
        if (tid < NCH){
            Params P = load_params(tid, m0,b0,f0, m1,b1,f1, m2,b2,f2, m3,b3);
            #pragma unroll
            for (int j = 0; j < 3; ++j){
                float target = (j==0) ? -QT : ((j==1) ? 0.0f : QT);
                sum += fabsf(eval_mlp<true>(q[tid*3+j], P) - target);
            }
        }
        #pragma unroll
        for (int off = 32; off > 0; off >>= 1)
            sum += __shfl_down(sum, off, 64);
        __shared__ float red[4];
        if ((tid & 63) == 0) red[tid >> 6] = sum;
        __syncthreads();
        if (tid == 0) *loss = red[0]+red[1]+red[2]+red[3];
        return;
    }

    // --------------------- nonlinear fallback (rare path) ----------------------
    const int c = blk - 1;                   // one block per channel
    float fs = 0.0f;
    #pragma unroll
    for (int k=0;k<3;k++) fs += fabsf(f0[c*3+k]) + fabsf(f1[c*3+k]) + fabsf(f2[c*3+k]);
    if (fs == 0.0f) return;                  // fast path handled this channel

    Params P = load_params(c, m0,b0,f0, m1,b1,f1, m2,b2,f2, m3,b3);

    const int end = (c+1)*CV4;
    for (int i = c*CV4 + tid; i < end; i += THREADS){
        v4f xv = x4[i], nv = n4[i];
        v4f ov, lv;
        #pragma unroll
        for (int e = 0; e < 4; ++e){
            float o  = xv[e] + nv[e] - 0.5f;
            float lo = eval_mlp<true>(o - 0.5f, P);
            float hi = eval_mlp<true>(o + 0.5f, P);
            ov[e] = o;
            lv[e] = lik_from_logits(lo, hi);
        }
        __builtin_nontemporal_store(ov, o4 + i);
        __builtin_nontemporal_store(lv, l4 + i);
    }
}

extern "C" void kernel_launch(void* const* d_in, const int* in_sizes, int n_in,
                              void* d_out, int out_size, void* d_ws, size_t ws_size,
                              hipStream_t stream) {
    // setup_inputs() dict order:
    // 0:x 1:noise 2:m0 3:b0 4:f0 5:m1 6:b1 7:f1 8:m2 9:b2 10:f2 11:m3 12:b3 13:quantiles
    const float* x  = (const float*)d_in[0];
    const float* nz = (const float*)d_in[1];
    const float* m0 = (const float*)d_in[2];
    const float* b0 = (const float*)d_in[3];
    const float* f0 = (const float*)d_in[4];
    const float* m1 = (const float*)d_in[5];
    const float* b1 = (const float*)d_in[6];
    const float* f1 = (const float*)d_in[7];
    const float* m2 = (const float*)d_in[8];
    const float* b2 = (const float*)d_in[9];
    const float* f2 = (const float*)d_in[10];
    const float* m3 = (const float*)d_in[11];
    const float* b3 = (const float*)d_in[12];
    const float* qq = (const float*)d_in[13];

    float* out  = (float*)d_out;
    float* lik  = out + (size_t)NCH*SPATIAL;
    float* loss = lik + (size_t)NCH*SPATIAL;

    eb_fused<<<TAILB + MAIN_GRID, THREADS, 0, stream>>>(
        x, nz, m0,b0,f0, m1,b1,f1, m2,b2,f2, m3,b3, qq, loss, out, lik);
}

// Round 14
// 213.510 us; speedup vs baseline: 1.4017x; 1.0083x over previous
//
#include <hip/hip_runtime.h>
#include <math.h>

// Problem constants (SHAPE = (1, 128, 48, 48, 48), FILTERS = (1,3,3,3,1))
#define NCH      128
#define SPATIAL  110592            // 48*48*48
#define NV4      3538944           // NCH*SPATIAL/4 total float4 groups
#define CV4      27648             // SPATIAL/4 float4 groups per channel
#define FB       1024              // float4 groups per block (256 thr x 4)
#define MAIN_GRID 3456             // NV4 / FB (exact)
#define BPC      27                // CV4 / FB -> blocks per channel (exact: channel is block-uniform)
#define TAILB    129               // 1 loss block + 128 per-channel fallback blocks (mapped first)
#define THREADS  256

#define QT 21.416413017506358f     // log(2/1e-9 - 1)

typedef float v4f __attribute__((ext_vector_type(4)));

__device__ __forceinline__ float frcp(float x){ return __builtin_amdgcn_rcpf(x); }
__device__ __forceinline__ float ftanh(float x){ return 1.0f - 2.0f*frcp(__expf(2.0f*x) + 1.0f); }
__device__ __forceinline__ float fsig(float x){ return frcp(1.0f + __expf(-x)); }
// Cheap softplus: native v_log instead of libm log1pf (round-5 counters:
// VALUBusy 92% dominated by log1pf collapse; round-9 confirmed the fix:
// eb_fused 135.6 -> ~52us).
__device__ __forceinline__ float fsoftplus(float x){ return fmaxf(x, 0.0f) + __logf(1.0f + __expf(-fabsf(x))); }

struct Params {
    float w0[3], w1[9], w2[9], w3[3];
    float t0[3], t1[3], t2[3];
    float B0[3], B1[3], B2[3], B3;
};

__device__ __forceinline__ Params load_params(int c,
    const float* __restrict__ m0, const float* __restrict__ b0, const float* __restrict__ f0,
    const float* __restrict__ m1, const float* __restrict__ b1, const float* __restrict__ f1,
    const float* __restrict__ m2, const float* __restrict__ b2, const float* __restrict__ f2,
    const float* __restrict__ m3, const float* __restrict__ b3)
{
    Params P;
    #pragma unroll
    for (int k=0;k<3;k++) P.w0[k]=fsoftplus(m0[c*3+k]);
    #pragma unroll
    for (int k=0;k<9;k++) P.w1[k]=fsoftplus(m1[c*9+k]);
    #pragma unroll
    for (int k=0;k<9;k++) P.w2[k]=fsoftplus(m2[c*9+k]);
    #pragma unroll
    for (int k=0;k<3;k++) P.w3[k]=fsoftplus(m3[c*3+k]);
    #pragma unroll
    for (int k=0;k<3;k++) P.t0[k]=ftanh(f0[c*3+k]);
    #pragma unroll
    for (int k=0;k<3;k++) P.t1[k]=ftanh(f1[c*3+k]);
    #pragma unroll
    for (int k=0;k<3;k++) P.t2[k]=ftanh(f2[c*3+k]);
    #pragma unroll
    for (int k=0;k<3;k++) P.B0[k]=b0[c*3+k];
    #pragma unroll
    for (int k=0;k<3;k++) P.B1[k]=b1[c*3+k];
    #pragma unroll
    for (int k=0;k<3;k++) P.B2[k]=b2[c*3+k];
    P.B3 = b3[c];
    return P;
}

template<bool USE_F>
__device__ __forceinline__ float eval_mlp(float z, const Params& P){
    float h0 = fmaf(P.w0[0], z, P.B0[0]);
    float h1 = fmaf(P.w0[1], z, P.B0[1]);
    float h2 = fmaf(P.w0[2], z, P.B0[2]);
    if (USE_F){
        h0 = fmaf(P.t0[0], ftanh(h0), h0);
        h1 = fmaf(P.t0[1], ftanh(h1), h1);
        h2 = fmaf(P.t0[2], ftanh(h2), h2);
    }
    float g0 = fmaf(P.w1[0],h0, fmaf(P.w1[1],h1, fmaf(P.w1[2],h2, P.B1[0])));
    float g1 = fmaf(P.w1[3],h0, fmaf(P.w1[4],h1, fmaf(P.w1[5],h2, P.B1[1])));
    float g2 = fmaf(P.w1[6],h0, fmaf(P.w1[7],h1, fmaf(P.w1[8],h2, P.B1[2])));
    if (USE_F){
        g0 = fmaf(P.t1[0], ftanh(g0), g0);
        g1 = fmaf(P.t1[1], ftanh(g1), g1);
        g2 = fmaf(P.t1[2], ftanh(g2), g2);
    }
    h0 = fmaf(P.w2[0],g0, fmaf(P.w2[1],g1, fmaf(P.w2[2],g2, P.B2[0])));
    h1 = fmaf(P.w2[3],g0, fmaf(P.w2[4],g1, fmaf(P.w2[5],g2, P.B2[1])));
    h2 = fmaf(P.w2[6],g0, fmaf(P.w2[7],g1, fmaf(P.w2[8],g2, P.B2[2])));
    if (USE_F){
        h0 = fmaf(P.t2[0], ftanh(h0), h0);
        h1 = fmaf(P.t2[1], ftanh(h1), h1);
        h2 = fmaf(P.t2[2], ftanh(h2), h2);
    }
    return fmaf(P.w3[0],h0, fmaf(P.w3[1],h1, fmaf(P.w3[2],h2, P.B3)));
}

__device__ __forceinline__ float lik_from_logits(float lo, float hi){
    float su = lo + hi;
    float s  = (su > 0.0f) ? -1.0f : ((su < 0.0f) ? 1.0f : 0.0f);   // -sign(lo+hi)
    float a  = fsig(s*hi);
    float b  = fsig(s*lo);
    return fmaxf(fabsf(a - b), 1e-9f);        // LIKELIHOOD_BOUND
}

// ---------------------------------------------------------------------------
// Single fused kernel, grid = TAILB + MAIN_GRID.
//   block 0        : quantiles_loss
//   blocks 1..128  : nonlinear fallback for channel b-1 iff nonzero factors
//   blocks 129..   : streaming fast path.
// Round-9: eb_fused ~52us (est; fell out of top-5), memory floor ~26-36us.
// This round: (a) __launch_bounds__(256,4) caps VGPR at 128 (guards the
// 2-waves/SIMD occupancy cliff from 8 in-flight v4f); (b) one-exp/one-rcp
// likelihood: sig(s*hi)-sig(s*lo) = u*(k-1)/((1+u)(1+u*k)), u=e^{s*lo},
// k-1 channel-uniform (precomputed e^{+-A}-1, selected by sign(lo+hi)).
// Exact same real-arithmetic value as the reference sign-trick form;
// exponent bounded by A/2 (su<0 => lo<-A/2 => u<1; su>0 => u<e^{A/2}).
// ---------------------------------------------------------------------------
__global__ __launch_bounds__(THREADS, 4) void eb_fused(
    const float* __restrict__ x, const float* __restrict__ noise,
    const float* __restrict__ m0, const float* __restrict__ b0, const float* __restrict__ f0,
    const float* __restrict__ m1, const float* __restrict__ b1, const float* __restrict__ f1,
    const float* __restrict__ m2, const float* __restrict__ b2, const float* __restrict__ f2,
    const float* __restrict__ m3, const float* __restrict__ b3,
    const float* __restrict__ q, float* __restrict__ loss,
    float* __restrict__ out, float* __restrict__ lik)
{
    const int blk = blockIdx.x;
    const int tid = threadIdx.x;

    const v4f* __restrict__ x4 = (const v4f*)x;
    const v4f* __restrict__ n4 = (const v4f*)noise;
    v4f* __restrict__ o4 = (v4f*)out;
    v4f* __restrict__ l4 = (v4f*)lik;

    if (blk >= TAILB){
        // ------------------------- streaming fast path -------------------------
        const int b = blk - TAILB;
        const int c = b / BPC;               // block-uniform channel

        const int i0 = b * FB + tid;         // 4 chunks: i0 + k*THREADS

        // issue the full memory stream immediately; collapse hides under it
        v4f xa0 = __builtin_nontemporal_load(x4 + i0);
        v4f xa1 = __builtin_nontemporal_load(x4 + i0 + 1*THREADS);
        v4f xa2 = __builtin_nontemporal_load(x4 + i0 + 2*THREADS);
        v4f xa3 = __builtin_nontemporal_load(x4 + i0 + 3*THREADS);
        v4f na0 = __builtin_nontemporal_load(n4 + i0);
        v4f na1 = __builtin_nontemporal_load(n4 + i0 + 1*THREADS);
        v4f na2 = __builtin_nontemporal_load(n4 + i0 + 2*THREADS);
        v4f na3 = __builtin_nontemporal_load(n4 + i0 + 3*THREADS);

        // linearity check: all 9 factors of this channel zero? (uniform loads)
        float fs = 0.0f;
        #pragma unroll
        for (int k=0;k<3;k++) fs += fabsf(f0[c*3+k]) + fabsf(f1[c*3+k]) + fabsf(f2[c*3+k]);
        if (fs != 0.0f) return;              // fallback blocks own this channel

        // progressive affine collapse: logit(z) = A*z + B for this channel
        float a0 = fsoftplus(m0[c*3+0]), a1 = fsoftplus(m0[c*3+1]), a2 = fsoftplus(m0[c*3+2]);
        float o0 = b0[c*3+0],            o1 = b0[c*3+1],            o2 = b0[c*3+2];

        {   // layer 1
            float w00=fsoftplus(m1[c*9+0]), w01=fsoftplus(m1[c*9+1]), w02=fsoftplus(m1[c*9+2]);
            float w10=fsoftplus(m1[c*9+3]), w11=fsoftplus(m1[c*9+4]), w12=fsoftplus(m1[c*9+5]);
            float w20=fsoftplus(m1[c*9+6]), w21=fsoftplus(m1[c*9+7]), w22=fsoftplus(m1[c*9+8]);
            float na_0 = w00*a0 + w01*a1 + w02*a2;
            float na_1 = w10*a0 + w11*a1 + w12*a2;
            float na_2 = w20*a0 + w21*a1 + w22*a2;
            float no_0 = w00*o0 + w01*o1 + w02*o2 + b1[c*3+0];
            float no_1 = w10*o0 + w11*o1 + w12*o2 + b1[c*3+1];
            float no_2 = w20*o0 + w21*o1 + w22*o2 + b1[c*3+2];
            a0=na_0; a1=na_1; a2=na_2; o0=no_0; o1=no_1; o2=no_2;
        }
        {   // layer 2
            float w00=fsoftplus(m2[c*9+0]), w01=fsoftplus(m2[c*9+1]), w02=fsoftplus(m2[c*9+2]);
            float w10=fsoftplus(m2[c*9+3]), w11=fsoftplus(m2[c*9+4]), w12=fsoftplus(m2[c*9+5]);
            float w20=fsoftplus(m2[c*9+6]), w21=fsoftplus(m2[c*9+7]), w22=fsoftplus(m2[c*9+8]);
            float na_0 = w00*a0 + w01*a1 + w02*a2;
            float na_1 = w10*a0 + w11*a1 + w12*a2;
            float na_2 = w20*a0 + w21*a1 + w22*a2;
            float no_0 = w00*o0 + w01*o1 + w02*o2 + b2[c*3+0];
            float no_1 = w10*o0 + w11*o1 + w12*o2 + b2[c*3+1];
            float no_2 = w20*o0 + w21*o1 + w22*o2 + b2[c*3+2];
            a0=na_0; a1=na_1; a2=na_2; o0=no_0; o1=no_1; o2=no_2;
        }
        float w30=fsoftplus(m3[c*3+0]), w31=fsoftplus(m3[c*3+1]), w32=fsoftplus(m3[c*3+2]);
        const float A  = w30*a0 + w31*a1 + w32*a2;
        const float Bq = w30*o0 + w31*o1 + w32*o2 + b3[c];
        const float Bl = Bq - 0.5f*A;        // logit(o-0.5) = A*o + Bl

        // channel-uniform likelihood constants: k-1 for s=+1 and s=-1
        const float kp = __expf(A)  - 1.0f;  // s=+1: k=e^{A}
        const float km = __expf(-A) - 1.0f;  // s=-1: k=e^{-A}

        #pragma unroll
        for (int k = 0; k < 4; ++k){
            v4f xv = (k==0)?xa0:((k==1)?xa1:((k==2)?xa2:xa3));
            v4f nv = (k==0)?na0:((k==1)?na1:((k==2)?na2:na3));
            v4f ov, lv;
            #pragma unroll
            for (int e = 0; e < 4; ++e){
                float o   = xv[e] + nv[e] - 0.5f;
                float lo  = fmaf(A, o, Bl);            // logit(o-0.5)
                float su  = fmaf(2.0f, lo, A);         // lo + hi
                // s = -sign(su); select k-1 and s*lo branchlessly
                float km1 = (su < 0.0f) ? kp : ((su > 0.0f) ? km : 0.0f);
                float sl  = (su < 0.0f) ? lo : ((su > 0.0f) ? -lo : 0.0f);
                float u   = __expf(sl);                // e^{s*lo}, bounded by e^{A/2}
                float num = u * km1;                   // u*(k-1) = uk - u
                float den = (1.0f + u) * (1.0f + (u + num));
                ov[e] = o;
                lv[e] = fmaxf(fabsf(num) * frcp(den), 1e-9f);
            }
            __builtin_nontemporal_store(ov, o4 + i0 + k*THREADS);
            __builtin_nontemporal_store(lv, l4 + i0 + k*THREADS);
        }
        return;
    }

    if (blk == 0){
        // ------------------------- quantiles_loss block ------------------------
        float sum = 0.0f;
        if (tid < NCH){
            Params P = load_params(tid, m0,b0,f0, m1,b1,f1, m2,b2,f2, m3,b3);
            #pragma unroll
            for (int j = 0; j < 3; ++j){
                float target = (j==0) ? -QT : ((j==1) ? 0.0f : QT);
                sum += fabsf(eval_mlp<true>(q[tid*3+j], P) - target);
            }
        }
        #pragma unroll
        for (int off = 32; off > 0; off >>= 1)
            sum += __shfl_down(sum, off, 64);
        __shared__ float red[4];
        if ((tid & 63) == 0) red[tid >> 6] = sum;
        __syncthreads();
        if (tid == 0) *loss = red[0]+red[1]+red[2]+red[3];
        return;
    }

    // --------------------- nonlinear fallback (rare path) ----------------------
    const int c = blk - 1;                   // one block per channel
    float fs = 0.0f;
    #pragma unroll
    for (int k=0;k<3;k++) fs += fabsf(f0[c*3+k]) + fabsf(f1[c*3+k]) + fabsf(f2[c*3+k]);
    if (fs == 0.0f) return;                  // fast path handled this channel

    Params P = load_params(c, m0,b0,f0, m1,b1,f1, m2,b2,f2, m3,b3);

    const int end = (c+1)*CV4;
    for (int i = c*CV4 + tid; i < end; i += THREADS){
        v4f xv = x4[i], nv = n4[i];
        v4f ov, lv;
        #pragma unroll
        for (int e = 0; e < 4; ++e){
            float o  = xv[e] + nv[e] - 0.5f;
            float lo = eval_mlp<true>(o - 0.5f, P);
            float hi = eval_mlp<true>(o + 0.5f, P);
            ov[e] = o;
            lv[e] = lik_from_logits(lo, hi);
        }
        __builtin_nontemporal_store(ov, o4 + i);
        __builtin_nontemporal_store(lv, l4 + i);
    }
}

extern "C" void kernel_launch(void* const* d_in, const int* in_sizes, int n_in,
                              void* d_out, int out_size, void* d_ws, size_t ws_size,
                              hipStream_t stream) {
    // setup_inputs() dict order:
    // 0:x 1:noise 2:m0 3:b0 4:f0 5:m1 6:b1 7:f1 8:m2 9:b2 10:f2 11:m3 12:b3 13:quantiles
    const float* x  = (const float*)d_in[0];
    const float* nz = (const float*)d_in[1];
    const float* m0 = (const float*)d_in[2];
    const float* b0 = (const float*)d_in[3];
    const float* f0 = (const float*)d_in[4];
    const float* m1 = (const float*)d_in[5];
    const float* b1 = (const float*)d_in[6];
    const float* f1 = (const float*)d_in[7];
    const float* m2 = (const float*)d_in[8];
    const float* b2 = (const float*)d_in[9];
    const float* f2 = (const float*)d_in[10];
    const float* m3 = (const float*)d_in[11];
    const float* b3 = (const float*)d_in[12];
    const float* qq = (const float*)d_in[13];

    float* out  = (float*)d_out;
    float* lik  = out + (size_t)NCH*SPATIAL;
    float* loss = lik + (size_t)NCH*SPATIAL;

    eb_fused<<<TAILB + MAIN_GRID, THREADS, 0, stream>>>(
        x, nz, m0,b0,f0, m1,b1,f1, m2,b2,f2, m3,b3, qq, loss, out, lik);
}